// Round 3
// baseline (10464.992 us; speedup 1.0000x reference)
//
#include <hip/hip_runtime.h>

typedef unsigned short u16;
typedef __bf16 bf16x8 __attribute__((ext_vector_type(8)));
typedef float f32x4 __attribute__((ext_vector_type(4)));

#define AS1 __attribute__((address_space(1)))
#define AS3 __attribute__((address_space(3)))

// B=256, A=5, T=64, NIN=4, NHID=256, L=2, H=1280, 4H=5120, steps=63

__device__ __forceinline__ u16 f2bf(float f) {
    union { float f; unsigned int u; } v; v.f = f;
    unsigned int r = v.u + 0x7fffu + ((v.u >> 16) & 1u);
    return (u16)(r >> 16);
}

__device__ __forceinline__ void ld_lds16(const u16* g, u16* l) {
    __builtin_amdgcn_global_load_lds((AS1 unsigned int*)(unsigned long long)(const void*)g,
                                     (AS3 unsigned int*)l, 16, 0, 0);
}

__device__ __forceinline__ float sigm(float x) { return 1.f / (1.f + __expf(-x)); }
__device__ __forceinline__ float tanh_f(float x) { return 1.f - 2.f / (__expf(2.f * x) + 1.f); }

// ---------------------------------------------------------------------------
// Weight-prep kernels (run once per launch, massively parallel)
// ---------------------------------------------------------------------------
__global__ __launch_bounds__(256) void cvt_kernel(const float* __restrict__ src,
                                                  u16* __restrict__ dst, int n) {
    int i = (blockIdx.x * 256 + threadIdx.x) * 4;
    if (i >= n) return;
    float4 v = *(const float4*)(src + i);
    ushort4 o;
    o.x = f2bf(v.x); o.y = f2bf(v.y); o.z = f2bf(v.z); o.w = f2bf(v.w);
    *(ushort4*)(dst + i) = o;
}

// wcat[l][j*4+g][k]: k<1280 -> w_ih[l][g*1280+j][k], else w_hh[..][k-1280]
__global__ __launch_bounds__(256) void cvt_wcat(const float* __restrict__ wih,
                                                const float* __restrict__ whh,
                                                u16* __restrict__ dst) {
    long long idx = ((long long)blockIdx.x * 256 + threadIdx.x) * 4;
    int k = (int)(idx % 2560);
    long long rr = idx / 2560;
    int l = (int)(rr / 5120), r = (int)(rr % 5120);
    int j = r >> 2, g = r & 3;
    long long srow = (long long)l * 5120 + g * 1280 + j;
    const float* s = (k < 1280) ? (wih + srow * 1280 + k) : (whh + srow * 1280 + (k - 1280));
    float4 v = *(const float4*)s;
    ushort4 o;
    o.x = f2bf(v.x); o.y = f2bf(v.y); o.z = f2bf(v.z); o.w = f2bf(v.w);
    *(ushort4*)(dst + idx) = o;
}

// w12p[kk][j] = pack(bf(w1_2[j][2kk]), bf(w1_2[j][2kk+1]))  (k-pair transposed)
__global__ __launch_bounds__(256) void cvt_w12p(const float* __restrict__ w,
                                                unsigned int* __restrict__ dst) {
    int idx = blockIdx.x * 256 + threadIdx.x;  // 32768
    int kk = idx >> 8, j = idx & 255;
    float f0 = w[j * 256 + 2 * kk], f1 = w[j * 256 + 2 * kk + 1];
    dst[idx] = (unsigned)f2bf(f0) | ((unsigned)f2bf(f1) << 16);
}

// ---------------------------------------------------------------------------
// Grid barrier: monotonic counter, no reset (race-free across rounds).
// Release: __threadfence (wbl2) before add; acquire: __threadfence (inv) after.
// ---------------------------------------------------------------------------
__device__ __forceinline__ void gbar(unsigned int* cnt, unsigned int target) {
    __syncthreads();
    if (threadIdx.x == 0) {
        __threadfence();
        __hip_atomic_fetch_add(cnt, 1u, __ATOMIC_RELAXED, __HIP_MEMORY_SCOPE_AGENT);
        while (__hip_atomic_load(cnt, __ATOMIC_RELAXED, __HIP_MEMORY_SCOPE_AGENT) < target)
            __builtin_amdgcn_s_sleep(2);
        __threadfence();
    }
    __syncthreads();
}

// ---------------------------------------------------------------------------
// Pipelined MFMA core, templated on B-chunks (BN = BCH*32). BM=64, BK=64.
// Double-buffered global_load_lds + manual vmcnt + raw s_barrier.
// XOR-swizzled LDS; per-wave (2 x BCH) 16x16x32 fragments.
// ---------------------------------------------------------------------------
template <int BCH>
__device__ __forceinline__ void gemm_core_t(
    const u16* A, int lda, const u16* Bw, int ldb, int K,
    int m0, int n0, u16* As, u16* Bs, f32x4 (&acc)[2][4]) {
    int tid = threadIdx.x;
    int w = tid >> 6, l = tid & 63;
    int wm = w >> 1, wn = w & 1;
    int q = l >> 4, m16 = l & 15;
    int r8 = l >> 3;
    int g8 = (l & 7) ^ r8;

    const u16* aP = A + (size_t)(m0 + w * 8 + r8) * lda + g8 * 8;
    const u16* bP = Bw + (size_t)(n0 + w * 8 + r8) * ldb + g8 * 8;
    u16* aD = As + w * 512;
    u16* bD = Bs + w * 512;

    int nIter = K >> 6;
    // prologue
    ld_lds16(aP, aD);
    ld_lds16(aP + (size_t)32 * lda, aD + 2048);
#pragma unroll
    for (int c = 0; c < BCH; c++)
        ld_lds16(bP + (size_t)(c * 32) * ldb, bD + c * 2048);

    for (int it = 0; it < nIter; ++it) {
        if (it + 1 < nIter) {
            int kt = (it + 1) << 6;
            int bsel = (it + 1) & 1;
            u16* ad = aD + bsel * 4096;
            u16* bd = bD + bsel * (BCH * 2048);
            const u16* ap = aP + kt;
            const u16* bp = bP + kt;
            ld_lds16(ap, ad);
            ld_lds16(ap + (size_t)32 * lda, ad + 2048);
#pragma unroll
            for (int c = 0; c < BCH; c++)
                ld_lds16(bp + (size_t)(c * 32) * ldb, bd + c * 2048);
            if (BCH == 4) asm volatile("s_waitcnt vmcnt(6)" ::: "memory");
            else          asm volatile("s_waitcnt vmcnt(4)" ::: "memory");
        } else {
            asm volatile("s_waitcnt vmcnt(0)" ::: "memory");
        }
        asm volatile("s_barrier" ::: "memory");
        const u16* as = As + (it & 1) * 4096;
        const u16* bs = Bs + (it & 1) * (BCH * 2048);
#pragma unroll
        for (int ks = 0; ks < 2; ks++) {
            bf16x8 af[2], bfr[4];
            int gsw = (ks * 4 + q) ^ (m16 & 7);
#pragma unroll
            for (int i = 0; i < 2; i++) {
                int m = wm * 32 + i * 16 + m16;
                af[i] = *(const bf16x8*)&as[m * 64 + gsw * 8];
            }
#pragma unroll
            for (int j = 0; j < BCH; j++) {
                int n = wn * (BCH * 16) + j * 16 + m16;
                bfr[j] = *(const bf16x8*)&bs[n * 64 + gsw * 8];
            }
#pragma unroll
            for (int i = 0; i < 2; i++)
#pragma unroll
                for (int j = 0; j < BCH; j++)
                    acc[i][j] = __builtin_amdgcn_mfma_f32_16x16x32_bf16(af[i], bfr[j], acc[i][j], 0, 0, 0);
        }
        asm volatile("s_barrier" ::: "memory");
    }
}

// ---------------------------------------------------------------------------
// Phase A/B: gates GEMM (64x128 tile, K=2560) + fused LSTM cell.
// blk < 160: nb=blk%40, mb=blk/40.
// ---------------------------------------------------------------------------
__device__ void phaseAB(int blk, const u16* A, const u16* Bw,
                        const float* bih, const float* bhh,
                        float* cst, u16* hA, u16* hB, char* smem) {
    u16* As = (u16*)smem;
    u16* Bs = (u16*)(smem + 16384);
    float (*cb)[132] = (float(*)[132])smem;  // overlay, used after core

    int nb = blk % 40, mb = blk / 40;
    int n0 = nb * 128, m0 = mb * 64;

    f32x4 acc[2][4];
#pragma unroll
    for (int i = 0; i < 2; i++)
#pragma unroll
        for (int j = 0; j < 4; j++) acc[i][j] = (f32x4){0.f, 0.f, 0.f, 0.f};

    gemm_core_t<4>(A, 2560, Bw, 2560, 2560, m0, n0, As, Bs, acc);

    int tid = threadIdx.x;
    int w = tid >> 6, l = tid & 63;
    int wm = w >> 1, wn = w & 1, q = l >> 4, m16 = l & 15;
#pragma unroll
    for (int i = 0; i < 2; i++)
#pragma unroll
        for (int j = 0; j < 4; j++)
#pragma unroll
            for (int r = 0; r < 4; r++)
                cb[wm * 32 + i * 16 + q * 4 + r][wn * 64 + j * 16 + m16] = acc[i][j][r];
    __syncthreads();

    int jt = tid & 31, bt0 = tid >> 5;
    int jg = (n0 >> 2) + jt;
    float bI = bih[jg] + bhh[jg];
    float bF = bih[1280 + jg] + bhh[1280 + jg];
    float bG = bih[2560 + jg] + bhh[2560 + jg];
    float bO = bih[3840 + jg] + bhh[3840 + jg];
#pragma unroll
    for (int p = 0; p < 8; p++) {
        int bt = bt0 + p * 8;
        float4 g4 = *(const float4*)&cb[bt][jt * 4];   // i,f,g,o
        int b = m0 + bt;
        float cv = cst[b * 1280 + jg];
        float cn = sigm(g4.y + bF) * cv + sigm(g4.x + bI) * tanh_f(g4.z + bG);
        cst[b * 1280 + jg] = cn;
        u16 hv = f2bf(sigm(g4.w + bO) * tanh_f(cn));
        hA[(size_t)b * 2560 + jg] = hv;
        if (hB) hB[(size_t)b * 2560 + jg] = hv;
    }
}

// ---------------------------------------------------------------------------
// Phase C: y = relu(h1 @ w21^T + b21), 64x64 tiles, K=1280. blk < 80.
// ---------------------------------------------------------------------------
__device__ void phaseC(int blk, const u16* A, const u16* w21,
                       const float* b21, float* yb, char* smem) {
    u16* As = (u16*)smem;
    u16* Bs = (u16*)(smem + 16384);
    int nb = blk % 20, mb = blk / 20;
    int n0 = nb * 64, m0 = mb * 64;

    f32x4 acc[2][4];
#pragma unroll
    for (int i = 0; i < 2; i++)
#pragma unroll
        for (int j = 0; j < 4; j++) acc[i][j] = (f32x4){0.f, 0.f, 0.f, 0.f};

    gemm_core_t<2>(A, 2560, w21, 1280, 1280, m0, n0, As, Bs, acc);

    int tid = threadIdx.x;
    int w = tid >> 6, l = tid & 63;
    int wm = w >> 1, wn = w & 1, q = l >> 4, m16 = l & 15;
#pragma unroll
    for (int i = 0; i < 2; i++) {
        int row = m0 + wm * 32 + i * 16 + q * 4;
#pragma unroll
        for (int j = 0; j < 2; j++) {
            int col = n0 + wn * 32 + j * 16 + m16;
#pragma unroll
            for (int r = 0; r < 4; r++)
                yb[(size_t)(row + r) * 1280 + col] = fmaxf(acc[i][j][r] + b21[col], 0.f);
        }
    }
}

// ---------------------------------------------------------------------------
// Phase D (per-sample, all 256 blocks): out head + residual + teacher select
// + MLP layer-1 + MLP layer-2 -> x(t+1) bf16 into xh0 next.
// ---------------------------------------------------------------------------
template <int FIRST>
__device__ void phaseD(int b, int t, int psv,
                       const float* yb, const float* w22, const float* b22,
                       const float* inputs, const float* w11, const float* b11,
                       const unsigned int* w12p, const float* b12,
                       float* out, float* ins_buf, u16* xnext, char* smem) {
    float* ins_s = (float*)smem;                       // 20 f
    float* act1 = (float*)(smem + 128);                // [5][256] f
    float (*red)[20] = (float(*)[20])(smem + 128 + 5120);
    int tid = threadIdx.x;
    int w = tid >> 6, l = tid & 63;

    if (!FIRST) {
        float acc[20];
#pragma unroll
        for (int j = 0; j < 20; j++) acc[j] = 0.f;
        const float* yrow = yb + (size_t)b * 1280;
#pragma unroll
        for (int s = 0; s < 5; s++) {
            int k = w * 320 + s * 64 + l;
            float yv = yrow[k];
#pragma unroll
            for (int j = 0; j < 20; j++) acc[j] = fmaf(yv, w22[j * 1280 + k], acc[j]);
        }
#pragma unroll
        for (int j = 0; j < 20; j++)
#pragma unroll
            for (int off = 32; off; off >>= 1) acc[j] += __shfl_xor(acc[j], off);
        if (l < 20) red[w][l] = acc[l];
        __syncthreads();
        if (tid < 20) {
            float o = red[0][tid] + red[1][tid] + red[2][tid] + red[3][tid]
                      + b22[tid] + ins_buf[b * 20 + tid];
            int a = tid >> 2, n = tid & 3;
            out[(((size_t)b * 5 + a) * 63 + t) * 4 + n] = o;
            float nx = (((t + 1) % psv) == 0)
                           ? inputs[(((size_t)b * 5 + a) * 64 + (t + 1)) * 4 + n] : o;
            ins_s[tid] = nx;
            ins_buf[b * 20 + tid] = nx;
        }
    } else {
        if (tid < 20) {
            int a = tid >> 2, n = tid & 3;
            float nx = inputs[(((size_t)b * 5 + a) * 64) * 4 + n];
            ins_s[tid] = nx;
            ins_buf[b * 20 + tid] = nx;
        }
    }
    __syncthreads();

    // MLP layer-1
    int j = tid;
    float4 wv = *(const float4*)(w11 + j * 4);
    float bb = b11[j];
#pragma unroll
    for (int g = 0; g < 5; g++) {
        float v = fmaf(wv.x, ins_s[g * 4],
                  fmaf(wv.y, ins_s[g * 4 + 1],
                  fmaf(wv.z, ins_s[g * 4 + 2],
                  fmaf(wv.w, ins_s[g * 4 + 3], bb))));
        act1[g * 256 + j] = fmaxf(v, 0.f);
    }
    __syncthreads();

    // MLP layer-2: x[g][j] = relu(sum_k act1[g][k]*w12[j][k] + b12[j])
    float acc2[5];
    float bb2 = b12[j];
#pragma unroll
    for (int g = 0; g < 5; g++) acc2[g] = bb2;
    for (int kk = 0; kk < 128; kk++) {
        unsigned int pr = w12p[kk * 256 + j];
        union { unsigned int u; float f; } lo, hi;
        lo.u = pr << 16; hi.u = pr & 0xffff0000u;
#pragma unroll
        for (int g = 0; g < 5; g++)
            acc2[g] = fmaf(lo.f, act1[g * 256 + 2 * kk],
                      fmaf(hi.f, act1[g * 256 + 2 * kk + 1], acc2[g]));
    }
#pragma unroll
    for (int g = 0; g < 5; g++)
        xnext[(size_t)b * 2560 + g * 256 + j] = f2bf(fmaxf(acc2[g], 0.f));
    __syncthreads();
}

// ---------------------------------------------------------------------------
// The persistent kernel: whole 63-step scan, 256 blocks, grid barriers.
// ---------------------------------------------------------------------------
__global__ __launch_bounds__(256) void persist(
    const float* __restrict__ inputs,
    const float* __restrict__ w11, const float* __restrict__ b11,
    const unsigned int* __restrict__ w12p, const float* __restrict__ b12,
    const u16* __restrict__ wcat,
    const float* __restrict__ bih, const float* __restrict__ bhh,
    const u16* __restrict__ w21bf, const float* __restrict__ b21,
    const float* __restrict__ w22, const float* __restrict__ b22,
    const int* __restrict__ ps,
    u16* xh0a, u16* xh0b, u16* xh1a, u16* xh1b,
    float* cst, float* yb, float* ins_buf, float* out,
    unsigned int* bar) {
    __shared__ __align__(16) char smem[49152];
    int blk = blockIdx.x;
    int psv = ps[0];
    u16* xh0[2] = {xh0a, xh0b};
    u16* xh1[2] = {xh1a, xh1b};
    unsigned int rnd = 0;

    // t = -1: select ins(0), MLP1+MLP2 -> x(0) into xh0[0]
    phaseD<1>(blk, -1, psv, yb, w22, b22, inputs, w11, b11, w12p, b12,
              out, ins_buf, xh0[0], smem);
    rnd++; gbar(bar, rnd * 256u);

    for (int t = 0; t < 63; t++) {
        int p = t & 1;
        if (blk < 160)
            phaseAB(blk, xh0[p], wcat, bih, bhh, cst,
                    xh0[1 - p] + 1280, xh1[p], smem);
        rnd++; gbar(bar, rnd * 256u);
        if (blk < 160)
            phaseAB(blk, xh1[p], wcat + 13107200, bih + 5120, bhh + 5120,
                    cst + 327680, xh1[1 - p] + 1280, (u16*)nullptr, smem);
        rnd++; gbar(bar, rnd * 256u);
        if (blk < 80)
            phaseC(blk, xh1[1 - p] + 1280, w21bf, b21, yb, smem);
        rnd++; gbar(bar, rnd * 256u);
        phaseD<0>(blk, t, psv, yb, w22, b22, inputs, w11, b11, w12p, b12,
                  out, ins_buf, xh0[(t + 1) & 1], smem);
        if (t < 62) { rnd++; gbar(bar, rnd * 256u); }
    }
}

// ---------------------------------------------------------------------------
extern "C" void kernel_launch(void* const* d_in, const int* in_sizes, int n_in,
                              void* d_out, int out_size, void* d_ws, size_t ws_size,
                              hipStream_t stream) {
    const float* inputs = (const float*)d_in[0];
    const float* w1_1 = (const float*)d_in[1];
    const float* b1_1 = (const float*)d_in[2];
    const float* w1_2 = (const float*)d_in[3];
    const float* b1_2 = (const float*)d_in[4];
    const float* w_ih = (const float*)d_in[5];
    const float* w_hh = (const float*)d_in[6];
    const float* b_ih = (const float*)d_in[7];
    const float* b_hh = (const float*)d_in[8];
    const float* w2_1 = (const float*)d_in[9];
    const float* b2_1 = (const float*)d_in[10];
    const float* w2_2 = (const float*)d_in[11];
    const float* b2_2 = (const float*)d_in[12];
    const int* ps = (const int*)d_in[13];
    float* out = (float*)d_out;

    char* ws = (char*)d_ws;
    size_t off = 0;
    auto alloc = [&](size_t bytes) -> void* {
        void* p = ws + off;
        off = (off + bytes + 255) & ~(size_t)255;
        return p;
    };
    u16* wcat = (u16*)alloc(26214400ull * 2);       // [2][5120][2560]
    u16* w21_bf = (u16*)alloc(1638400ull * 2);      // [1280][1280]
    unsigned int* w12p = (unsigned int*)alloc(32768ull * 4);  // [128][256] k-pairs
    u16* xh0a = (u16*)alloc(655360ull * 2);         // [256][2560] = [x | h0]
    u16* xh0b = (u16*)alloc(655360ull * 2);
    u16* xh1a = (u16*)alloc(655360ull * 2);         // [256][2560] = [h0 | h1]
    u16* xh1b = (u16*)alloc(655360ull * 2);
    float* c_st = (float*)alloc(655360ull * 4);     // [2][256][1280]
    float* yb = (float*)alloc(327680ull * 4);       // [256][1280]
    float* ins_b = (float*)alloc(5120ull * 4);      // [256][20]
    unsigned int* bar = (unsigned int*)alloc(256);

    // weight prep + state init
    cvt_wcat<<<25600, 256, 0, stream>>>(w_ih, w_hh, wcat);
    cvt_kernel<<<1600, 256, 0, stream>>>(w2_1, w21_bf, 1638400);
    cvt_w12p<<<128, 256, 0, stream>>>(w1_2, w12p);
    hipMemsetAsync(xh0a, 0, 655360ull * 2, stream);
    hipMemsetAsync(xh0b, 0, 655360ull * 2, stream);
    hipMemsetAsync(xh1a, 0, 655360ull * 2, stream);
    hipMemsetAsync(xh1b, 0, 655360ull * 2, stream);
    hipMemsetAsync(c_st, 0, 655360ull * 4, stream);
    hipMemsetAsync(bar, 0, 256, stream);

    persist<<<256, 256, 0, stream>>>(
        inputs, w1_1, b1_1, w12p, b1_2, wcat, b_ih, b_hh, w21_bf, b2_1,
        w2_2, b2_2, ps, xh0a, xh0b, xh1a, xh1b, c_st, yb, ins_b, out, bar);
}

// Round 4
// 3879.572 us; speedup vs baseline: 2.6975x; 2.6975x over previous
//
#include <hip/hip_runtime.h>

typedef unsigned short u16;
typedef __bf16 bf16x8 __attribute__((ext_vector_type(8)));
typedef float f32x4 __attribute__((ext_vector_type(4)));

#define AS1 __attribute__((address_space(1)))
#define AS3 __attribute__((address_space(3)))

// B=256, A=5, T=64, NIN=4, NHID=256, L=2, H=1280, 4H=5120, steps=63

__device__ __forceinline__ u16 f2bf(float f) {
    union { float f; unsigned int u; } v; v.f = f;
    unsigned int r = v.u + 0x7fffu + ((v.u >> 16) & 1u);
    return (u16)(r >> 16);
}

__device__ __forceinline__ void ld_lds16(const u16* g, u16* l) {
    __builtin_amdgcn_global_load_lds((AS1 unsigned int*)(unsigned long long)(const void*)g,
                                     (AS3 unsigned int*)l, 16, 0, 0);
}

__device__ __forceinline__ float sigm(float x) { return 1.f / (1.f + __expf(-x)); }
__device__ __forceinline__ float tanh_f(float x) { return 1.f - 2.f / (__expf(2.f * x) + 1.f); }

// ---------------------------------------------------------------------------
// Weight-prep kernels
// ---------------------------------------------------------------------------
__global__ __launch_bounds__(256) void cvt_kernel(const float* __restrict__ src,
                                                  u16* __restrict__ dst, int n) {
    int i = (blockIdx.x * 256 + threadIdx.x) * 4;
    if (i >= n) return;
    float4 v = *(const float4*)(src + i);
    ushort4 o;
    o.x = f2bf(v.x); o.y = f2bf(v.y); o.z = f2bf(v.z); o.w = f2bf(v.w);
    *(ushort4*)(dst + i) = o;
}

// wcat[l][j*4+g][k]: k<1280 -> w_ih[l][g*1280+j][k], else w_hh[..][k-1280]
__global__ __launch_bounds__(256) void cvt_wcat(const float* __restrict__ wih,
                                                const float* __restrict__ whh,
                                                u16* __restrict__ dst) {
    long long idx = ((long long)blockIdx.x * 256 + threadIdx.x) * 4;
    int k = (int)(idx % 2560);
    long long rr = idx / 2560;
    int l = (int)(rr / 5120), r = (int)(rr % 5120);
    int j = r >> 2, g = r & 3;
    long long srow = (long long)l * 5120 + g * 1280 + j;
    const float* s = (k < 1280) ? (wih + srow * 1280 + k) : (whh + srow * 1280 + (k - 1280));
    float4 v = *(const float4*)s;
    ushort4 o;
    o.x = f2bf(v.x); o.y = f2bf(v.y); o.z = f2bf(v.z); o.w = f2bf(v.w);
    *(ushort4*)(dst + idx) = o;
}

// w12p[kk][j] = pack(bf(w1_2[j][2kk]), bf(w1_2[j][2kk+1]))
__global__ __launch_bounds__(256) void cvt_w12p(const float* __restrict__ w,
                                                unsigned int* __restrict__ dst) {
    int idx = blockIdx.x * 256 + threadIdx.x;  // 32768
    int kk = idx >> 8, j = idx & 255;
    float f0 = w[j * 256 + 2 * kk], f1 = w[j * 256 + 2 * kk + 1];
    dst[idx] = (unsigned)f2bf(f0) | ((unsigned)f2bf(f1) << 16);
}

// ---------------------------------------------------------------------------
// core64: 64x128 tile, K=1280 (20 iters), BK=64, triple-buffered prefetch
// (depth 2), XOR-swizzled LDS, explicit vmcnt + s_barrier.
// As: 3 x 4096 u16 (24KB), Bs: 3 x 8192 u16 (48KB).
// ---------------------------------------------------------------------------
__device__ __forceinline__ void core64(
    const u16* A, int lda, const u16* Bw, int ldb,
    int m0, int n0, u16* As, u16* Bs, f32x4 (&acc)[2][4]) {
    const int nIter = 20;
    int tid = threadIdx.x;
    int w = tid >> 6, l = tid & 63;
    int r8 = l >> 3, g8 = (l & 7) ^ r8;
    const u16* aP = A + (size_t)(m0 + w * 8 + r8) * lda + g8 * 8;
    const u16* bP = Bw + (size_t)(n0 + w * 8 + r8) * ldb + g8 * 8;
    u16* aD = As + w * 512;
    u16* bD = Bs + w * 512;

#define ISSUE64(it)                                            \
    {                                                          \
        int bsel = (it) % 3;                                   \
        const u16* ap = aP + (it) * 64;                        \
        const u16* bp = bP + (it) * 64;                        \
        u16* ad = aD + bsel * 4096;                            \
        u16* bd = bD + bsel * 8192;                            \
        ld_lds16(ap, ad);                                      \
        ld_lds16(ap + (size_t)32 * lda, ad + 2048);            \
        ld_lds16(bp, bd);                                      \
        ld_lds16(bp + (size_t)32 * ldb, bd + 2048);            \
        ld_lds16(bp + (size_t)64 * ldb, bd + 4096);            \
        ld_lds16(bp + (size_t)96 * ldb, bd + 6144);            \
    }

    ISSUE64(0);
    ISSUE64(1);
    int wm = w >> 1, wn = w & 1, q = l >> 4, m16 = l & 15;
    for (int it = 0; it < nIter; ++it) {
        if (it + 2 < nIter) ISSUE64(it + 2);
        int ahead = nIter - 1 - it; if (ahead > 2) ahead = 2;
        if (ahead == 2) asm volatile("s_waitcnt vmcnt(12)" ::: "memory");
        else if (ahead == 1) asm volatile("s_waitcnt vmcnt(6)" ::: "memory");
        else asm volatile("s_waitcnt vmcnt(0)" ::: "memory");
        asm volatile("s_barrier" ::: "memory");
        const u16* as = As + (it % 3) * 4096;
        const u16* bs = Bs + (it % 3) * 8192;
#pragma unroll
        for (int ks = 0; ks < 2; ks++) {
            bf16x8 af[2], bfr[4];
            int gsw = (ks * 4 + q) ^ (m16 & 7);
#pragma unroll
            for (int i = 0; i < 2; i++) {
                int m = wm * 32 + i * 16 + m16;
                af[i] = *(const bf16x8*)&as[m * 64 + gsw * 8];
            }
#pragma unroll
            for (int j = 0; j < 4; j++) {
                int n = wn * 64 + j * 16 + m16;
                bfr[j] = *(const bf16x8*)&bs[n * 64 + gsw * 8];
            }
#pragma unroll
            for (int i = 0; i < 2; i++)
#pragma unroll
                for (int j = 0; j < 4; j++)
                    acc[i][j] = __builtin_amdgcn_mfma_f32_16x16x32_bf16(af[i], bfr[j], acc[i][j], 0, 0, 0);
        }
        asm volatile("s_barrier" ::: "memory");
    }
#undef ISSUE64
}

// ---------------------------------------------------------------------------
// core128: 128x128 tile, K=1280 (20 iters), wave-tile 64x64 (2x2 waves),
// triple-buffered. As/Bs: 3 x 8192 u16 (48KB each).
// ---------------------------------------------------------------------------
__device__ __forceinline__ void core128(
    const u16* A, int lda, const u16* Bw, int ldb,
    int m0, int n0, u16* As, u16* Bs, f32x4 (&acc)[4][4]) {
    const int nIter = 20;
    int tid = threadIdx.x;
    int w = tid >> 6, l = tid & 63;
    int r8 = l >> 3, g8 = (l & 7) ^ r8;
    const u16* aP = A + (size_t)(m0 + w * 32 + r8) * lda + g8 * 8;
    const u16* bP = Bw + (size_t)(n0 + w * 32 + r8) * ldb + g8 * 8;
    u16* aD = As + w * 2048;
    u16* bD = Bs + w * 2048;

#define ISSUE128(it)                                           \
    {                                                          \
        int bsel = (it) % 3;                                   \
        const u16* ap = aP + (it) * 64;                        \
        const u16* bp = bP + (it) * 64;                        \
        u16* ad = aD + bsel * 8192;                            \
        u16* bd = bD + bsel * 8192;                            \
        ld_lds16(ap, ad);                                      \
        ld_lds16(ap + (size_t)8 * lda, ad + 512);              \
        ld_lds16(ap + (size_t)16 * lda, ad + 1024);            \
        ld_lds16(ap + (size_t)24 * lda, ad + 1536);            \
        ld_lds16(bp, bd);                                      \
        ld_lds16(bp + (size_t)8 * ldb, bd + 512);              \
        ld_lds16(bp + (size_t)16 * ldb, bd + 1024);            \
        ld_lds16(bp + (size_t)24 * ldb, bd + 1536);            \
    }

    ISSUE128(0);
    ISSUE128(1);
    int wm = w >> 1, wn = w & 1, q = l >> 4, m16 = l & 15;
    for (int it = 0; it < nIter; ++it) {
        if (it + 2 < nIter) ISSUE128(it + 2);
        int ahead = nIter - 1 - it; if (ahead > 2) ahead = 2;
        if (ahead == 2) asm volatile("s_waitcnt vmcnt(16)" ::: "memory");
        else if (ahead == 1) asm volatile("s_waitcnt vmcnt(8)" ::: "memory");
        else asm volatile("s_waitcnt vmcnt(0)" ::: "memory");
        asm volatile("s_barrier" ::: "memory");
        const u16* as = As + (it % 3) * 8192;
        const u16* bs = Bs + (it % 3) * 8192;
#pragma unroll
        for (int ks = 0; ks < 2; ks++) {
            bf16x8 af[4], bfr[4];
            int gsw = (ks * 4 + q) ^ (m16 & 7);
#pragma unroll
            for (int i = 0; i < 4; i++) {
                int m = wm * 64 + i * 16 + m16;
                af[i] = *(const bf16x8*)&as[m * 64 + gsw * 8];
            }
#pragma unroll
            for (int j = 0; j < 4; j++) {
                int n = wn * 64 + j * 16 + m16;
                bfr[j] = *(const bf16x8*)&bs[n * 64 + gsw * 8];
            }
#pragma unroll
            for (int i = 0; i < 4; i++)
#pragma unroll
                for (int j = 0; j < 4; j++)
                    acc[i][j] = __builtin_amdgcn_mfma_f32_16x16x32_bf16(af[i], bfr[j], acc[i][j], 0, 0, 0);
        }
        asm volatile("s_barrier" ::: "memory");
    }
#undef ISSUE128
}

// ---------------------------------------------------------------------------
// KA/KB: gates_l = A(x or h0)[256x1280] @ w_ih_l^T (K=1280) + ghh_l + cell.
// 160 blocks. Epilogue: LDS transpose + fused LSTM cell -> h (bf16, stride
// 1280) and c (fp32).
// ---------------------------------------------------------------------------
__global__ __launch_bounds__(256) void k_gates(
    const u16* __restrict__ A, const u16* __restrict__ Bw,
    const float* __restrict__ ghh,
    const float* __restrict__ bih, const float* __restrict__ bhh,
    float* __restrict__ cst, u16* __restrict__ hout) {
    __shared__ __align__(16) char smem[73728];
    u16* As = (u16*)smem;
    u16* Bs = (u16*)(smem + 24576);
    float (*cb)[132] = (float(*)[132])smem;   // overlay after core

    int blk = blockIdx.x;
    int nb = blk % 40, mb = blk / 40;
    int n0 = nb * 128, m0 = mb * 64;

    f32x4 acc[2][4];
#pragma unroll
    for (int i = 0; i < 2; i++)
#pragma unroll
        for (int j = 0; j < 4; j++) acc[i][j] = (f32x4){0.f, 0.f, 0.f, 0.f};

    core64(A, 1280, Bw, 2560, m0, n0, As, Bs, acc);

    int tid = threadIdx.x;
    int w = tid >> 6, l = tid & 63;
    int wm = w >> 1, wn = w & 1, q = l >> 4, m16 = l & 15;
#pragma unroll
    for (int i = 0; i < 2; i++)
#pragma unroll
        for (int j = 0; j < 4; j++)
#pragma unroll
            for (int r = 0; r < 4; r++) {
                int rl = wm * 32 + i * 16 + q * 4 + r;
                int cl = wn * 64 + j * 16 + m16;
                cb[rl][cl] = acc[i][j][r] + ghh[(size_t)(m0 + rl) * 5120 + n0 + cl];
            }
    __syncthreads();

    int jt = tid & 31, bt0 = tid >> 5;
    int jg = (n0 >> 2) + jt;
    float bI = bih[jg] + bhh[jg];
    float bF = bih[1280 + jg] + bhh[1280 + jg];
    float bG = bih[2560 + jg] + bhh[2560 + jg];
    float bO = bih[3840 + jg] + bhh[3840 + jg];
#pragma unroll
    for (int p = 0; p < 8; p++) {
        int bt = bt0 + p * 8;
        float4 g4 = *(const float4*)&cb[bt][jt * 4];   // i,f,g,o
        int b = m0 + bt;
        float cv = cst[b * 1280 + jg];
        float cn = sigm(g4.y + bF) * cv + sigm(g4.x + bI) * tanh_f(g4.z + bG);
        cst[b * 1280 + jg] = cn;
        hout[(size_t)b * 1280 + jg] = f2bf(sigm(g4.w + bO) * tanh_f(cn));
    }
}

// ---------------------------------------------------------------------------
// KC: blk<40: y = relu(h1 @ w21^T + b21) (64x128 tiles);
//     blk 40..199: ghh_l' = h_l @ w_hh_l^T (128x128 tiles) for next step.
// ---------------------------------------------------------------------------
__global__ __launch_bounds__(256) void k_c(
    const u16* __restrict__ h0, const u16* __restrict__ h1,
    const u16* __restrict__ w21, const float* __restrict__ b21,
    const u16* __restrict__ wcat,
    float* __restrict__ yb, float* __restrict__ ghh0, float* __restrict__ ghh1) {
    __shared__ __align__(16) char smem[98304];
    int blk = blockIdx.x;
    int tid = threadIdx.x;
    int w = tid >> 6, l = tid & 63;
    int wm = w >> 1, wn = w & 1, q = l >> 4, m16 = l & 15;

    if (blk < 40) {
        u16* As = (u16*)smem;
        u16* Bs = (u16*)(smem + 24576);
        int nb = blk % 10, mb = blk / 10;
        int n0 = nb * 128, m0 = mb * 64;
        f32x4 acc[2][4];
#pragma unroll
        for (int i = 0; i < 2; i++)
#pragma unroll
            for (int j = 0; j < 4; j++) acc[i][j] = (f32x4){0.f, 0.f, 0.f, 0.f};
        core64(h1, 1280, w21, 1280, m0, n0, As, Bs, acc);
#pragma unroll
        for (int i = 0; i < 2; i++) {
            int row = m0 + wm * 32 + i * 16 + q * 4;
#pragma unroll
            for (int j = 0; j < 4; j++) {
                int col = n0 + wn * 64 + j * 16 + m16;
#pragma unroll
                for (int r = 0; r < 4; r++)
                    yb[(size_t)(row + r) * 1280 + col] = fmaxf(acc[i][j][r] + b21[col], 0.f);
            }
        }
    } else {
        int task = blk - 40;
        int layer = task / 80, t2 = task % 80;
        int mb = t2 / 40, nb = t2 % 40;
        int m0 = mb * 128, n0 = nb * 128;
        const u16* Aop = layer ? h1 : h0;
        const u16* Bop = wcat + (size_t)layer * 13107200 + 1280;  // w_hh half
        float* G = layer ? ghh1 : ghh0;
        u16* As = (u16*)smem;
        u16* Bs = (u16*)(smem + 49152);
        f32x4 acc[4][4];
#pragma unroll
        for (int i = 0; i < 4; i++)
#pragma unroll
            for (int j = 0; j < 4; j++) acc[i][j] = (f32x4){0.f, 0.f, 0.f, 0.f};
        core128(Aop, 1280, Bop, 2560, m0, n0, As, Bs, acc);
#pragma unroll
        for (int i = 0; i < 4; i++) {
            int row = m0 + wm * 64 + i * 16 + q * 4;
#pragma unroll
            for (int j = 0; j < 4; j++) {
                int col = n0 + wn * 64 + j * 16 + m16;
#pragma unroll
                for (int r = 0; r < 4; r++)
                    G[(size_t)(row + r) * 5120 + col] = acc[i][j][r];
            }
        }
    }
}

// ---------------------------------------------------------------------------
// KD: out head (y@w22^T + b22 + ins) -> d_out, teacher-select ins(t+1),
// MLP layer-1, MLP layer-2 -> x(t+1) bf16 [256][1280]. 256 blocks (1/sample).
// ---------------------------------------------------------------------------
template <int FIRST>
__global__ __launch_bounds__(256) void k_out(
    const float* __restrict__ yb, const float* __restrict__ w22,
    const float* __restrict__ b22, const float* __restrict__ inputs,
    const int* __restrict__ ps, const float* __restrict__ w11,
    const float* __restrict__ b11, const unsigned int* __restrict__ w12p,
    const float* __restrict__ b12, float* __restrict__ out,
    float* __restrict__ ins_buf, u16* __restrict__ xnext, int t) {
    __shared__ float ins_s[20];
    __shared__ float act1[5 * 256];
    __shared__ float red[4][20];
    int b = blockIdx.x, tid = threadIdx.x;
    int w = tid >> 6, l = tid & 63;
    int psv = ps[0];

    if (!FIRST) {
        float acc[20];
#pragma unroll
        for (int j = 0; j < 20; j++) acc[j] = 0.f;
        const float* yrow = yb + (size_t)b * 1280;
#pragma unroll
        for (int s = 0; s < 5; s++) {
            int k = w * 320 + s * 64 + l;
            float yv = yrow[k];
#pragma unroll
            for (int j = 0; j < 20; j++) acc[j] = fmaf(yv, w22[j * 1280 + k], acc[j]);
        }
#pragma unroll
        for (int j = 0; j < 20; j++)
#pragma unroll
            for (int off = 32; off; off >>= 1) acc[j] += __shfl_xor(acc[j], off);
        if (l < 20) red[w][l] = acc[l];
        __syncthreads();
        if (tid < 20) {
            float o = red[0][tid] + red[1][tid] + red[2][tid] + red[3][tid]
                      + b22[tid] + ins_buf[b * 20 + tid];
            int a = tid >> 2, n = tid & 3;
            out[(((size_t)b * 5 + a) * 63 + t) * 4 + n] = o;
            float nx = (((t + 1) % psv) == 0)
                           ? inputs[(((size_t)b * 5 + a) * 64 + (t + 1)) * 4 + n] : o;
            ins_s[tid] = nx;
            ins_buf[b * 20 + tid] = nx;
        }
    } else {
        if (tid < 20) {
            int a = tid >> 2, n = tid & 3;
            float nx = inputs[(((size_t)b * 5 + a) * 64) * 4 + n];
            ins_s[tid] = nx;
            ins_buf[b * 20 + tid] = nx;
        }
    }
    __syncthreads();

    int j = tid;
    float4 wv = *(const float4*)(w11 + j * 4);
    float bb = b11[j];
#pragma unroll
    for (int g = 0; g < 5; g++) {
        float v = fmaf(wv.x, ins_s[g * 4],
                  fmaf(wv.y, ins_s[g * 4 + 1],
                  fmaf(wv.z, ins_s[g * 4 + 2],
                  fmaf(wv.w, ins_s[g * 4 + 3], bb))));
        act1[g * 256 + j] = fmaxf(v, 0.f);
    }
    __syncthreads();

    float acc2[5];
    float bb2 = b12[j];
#pragma unroll
    for (int g = 0; g < 5; g++) acc2[g] = bb2;
    for (int kk = 0; kk < 128; kk++) {
        unsigned int pr = w12p[kk * 256 + j];
        union { unsigned int u; float f; } lo, hi;
        lo.u = pr << 16; hi.u = pr & 0xffff0000u;
#pragma unroll
        for (int g = 0; g < 5; g++)
            acc2[g] = fmaf(lo.f, act1[g * 256 + 2 * kk],
                      fmaf(hi.f, act1[g * 256 + 2 * kk + 1], acc2[g]));
    }
#pragma unroll
    for (int g = 0; g < 5; g++)
        xnext[(size_t)b * 1280 + g * 256 + j] = f2bf(fmaxf(acc2[g], 0.f));
}

// ---------------------------------------------------------------------------
extern "C" void kernel_launch(void* const* d_in, const int* in_sizes, int n_in,
                              void* d_out, int out_size, void* d_ws, size_t ws_size,
                              hipStream_t stream) {
    const float* inputs = (const float*)d_in[0];
    const float* w1_1 = (const float*)d_in[1];
    const float* b1_1 = (const float*)d_in[2];
    const float* w1_2 = (const float*)d_in[3];
    const float* b1_2 = (const float*)d_in[4];
    const float* w_ih = (const float*)d_in[5];
    const float* w_hh = (const float*)d_in[6];
    const float* b_ih = (const float*)d_in[7];
    const float* b_hh = (const float*)d_in[8];
    const float* w2_1 = (const float*)d_in[9];
    const float* b2_1 = (const float*)d_in[10];
    const float* w2_2 = (const float*)d_in[11];
    const float* b2_2 = (const float*)d_in[12];
    const int* ps = (const int*)d_in[13];
    float* out = (float*)d_out;

    char* ws = (char*)d_ws;
    size_t off = 0;
    auto alloc = [&](size_t bytes) -> void* {
        void* p = ws + off;
        off = (off + bytes + 255) & ~(size_t)255;
        return p;
    };
    u16* wcat = (u16*)alloc(26214400ull * 2);        // [2][5120][2560]
    u16* w21_bf = (u16*)alloc(1638400ull * 2);       // [1280][1280]
    unsigned int* w12p = (unsigned int*)alloc(32768ull * 4);
    u16* xbf = (u16*)alloc(327680ull * 2);           // [256][1280]
    u16* h0 = (u16*)alloc(327680ull * 2);            // [256][1280]
    u16* h1 = (u16*)alloc(327680ull * 2);            // [256][1280]
    float* c0 = (float*)alloc(327680ull * 4);        // [256][1280]
    float* c1 = (float*)alloc(327680ull * 4);
    float* ghh0 = (float*)alloc(1310720ull * 4);     // [256][5120]
    float* ghh1 = (float*)alloc(1310720ull * 4);
    float* yb = (float*)alloc(327680ull * 4);        // [256][1280]
    float* ins_b = (float*)alloc(5120ull * 4);       // [256][20]

    // weight prep + state init
    cvt_wcat<<<25600, 256, 0, stream>>>(w_ih, w_hh, wcat);
    cvt_kernel<<<1600, 256, 0, stream>>>(w2_1, w21_bf, 1638400);
    cvt_w12p<<<128, 256, 0, stream>>>(w1_2, w12p);
    hipMemsetAsync(c0, 0, 327680ull * 4, stream);
    hipMemsetAsync(c1, 0, 327680ull * 4, stream);
    hipMemsetAsync(ghh0, 0, 1310720ull * 4, stream);
    hipMemsetAsync(ghh1, 0, 1310720ull * 4, stream);

    // t = -1: ins(0) select + MLP1 + MLP2 -> x(0)
    k_out<1><<<256, 256, 0, stream>>>(yb, w2_2, b2_2, inputs, ps, w1_1, b1_1,
                                      w12p, b1_2, out, ins_b, xbf, -1);

    for (int t = 0; t < 63; t++) {
        // KA: gates0 = x @ w_ih0^T + ghh0, fused cell -> h0, c0
        k_gates<<<160, 256, 0, stream>>>(xbf, wcat, ghh0, b_ih, b_hh, c0, h0);
        // KB: gates1 = h0 @ w_ih1^T + ghh1, fused cell -> h1, c1
        k_gates<<<160, 256, 0, stream>>>(h0, wcat + 13107200, ghh1,
                                         b_ih + 5120, b_hh + 5120, c1, h1);
        // KC: y = relu(h1 @ w21^T + b21)  ||  ghh0' = h0@w_hh0^T, ghh1' = h1@w_hh1^T
        k_c<<<200, 256, 0, stream>>>(h0, h1, w21_bf, b2_1, wcat, yb, ghh0, ghh1);
        // KD: out head + residual + ins(t+1) + MLP1 + MLP2 -> x(t+1)
        k_out<0><<<256, 256, 0, stream>>>(yb, w2_2, b2_2, inputs, ps, w1_1, b1_1,
                                          w12p, b1_2, out, ins_b, xbf, t);
    }
}